// Round 4
// baseline (508.609 us; speedup 1.0000x reference)
//
#include <hip/hip_runtime.h>

// B=32, LV=196, LT=40, D=512, H=8, DH=64

typedef unsigned int u32;
typedef unsigned short u16;
typedef __attribute__((ext_vector_type(8))) short bf16x8;
typedef __attribute__((ext_vector_type(4))) float f32x4;

#define DEV __device__ __forceinline__

DEV u16 f2bf(float f) {
  u32 u = __builtin_bit_cast(u32, f);
  u = (u + 0x7FFFu + ((u >> 16) & 1u)) >> 16;
  return (u16)u;
}
DEV float bf2f(u16 h) { u32 u = ((u32)h) << 16; return __builtin_bit_cast(float, u); }
// monotonic float<->u32 encoding for atomicMax on floats
DEV u32 encf(float f) { u32 u = __builtin_bit_cast(u32, f); return (u & 0x80000000u) ? ~u : (u | 0x80000000u); }
DEV float decf(u32 e) { u32 u = (e & 0x80000000u) ? (e & 0x7FFFFFFFu) : ~u; return __builtin_bit_cast(float, u); }
// NOTE: decf must invert encf exactly: enc: neg -> ~u ; pos -> u|0x8000_0000
DEV float decf2(u32 e) { u32 u = (e & 0x80000000u) ? (e & 0x7FFFFFFFu) : ~e; return __builtin_bit_cast(float, u); }

// async global->LDS, 16B per lane; LDS dst = base + lane*16 (wave-uniform base)
DEV void gll16(const u16* g, u16* l) {
  __builtin_amdgcn_global_load_lds((const __attribute__((address_space(1))) unsigned int*)g,
                                   (__attribute__((address_space(3))) unsigned int*)l, 16, 0, 0);
}

// ---------------- fused prep: all plain casts + conv1a split-cast + maxbuf zero ----------------
__global__ __launch_bounds__(256) void k_prep(const float* __restrict__ bef, const float* __restrict__ aft,
                                              const float* __restrict__ in_proj_w, const float* __restrict__ k_w,
                                              const float* __restrict__ q_w, const float* __restrict__ conv1_w,
                                              u16* __restrict__ bef16, u16* __restrict__ aft16,
                                              u16* __restrict__ inproj16, u16* __restrict__ kw16,
                                              u16* __restrict__ qw16, u16* __restrict__ w1a16,
                                              uint4* __restrict__ maxbuf) {
  int i = blockIdx.x * blockDim.x + threadIdx.x; // 0 .. 1,099,775
  const float* src; u16* dst; int j;
  if (i < 401408) { src = bef; dst = bef16; j = i; }
  else if (i < 802816) { src = aft; dst = aft16; j = i - 401408; }
  else if (i < 901120) { src = in_proj_w; dst = inproj16; j = i - 802816; }
  else if (i < 933888) { src = k_w; dst = kw16; j = i - 901120; }
  else if (i < 966656) { src = q_w; dst = qw16; j = i - 933888; }
  else if (i < 999424) {
    j = i - 966656; // conv1a: (512 x 1024) image half -> (512 x 512)
    int o = j >> 6, c0 = (j & 63) * 8;
    const float* p = conv1_w + (size_t)o * 1024 + c0;
    u16 t[8];
#pragma unroll
    for (int q = 0; q < 8; ++q) t[q] = f2bf(p[q]);
    *(uint4*)(w1a16 + (size_t)o * 512 + c0) = *(uint4*)t;
    return;
  } else {
    maxbuf[i - 999424] = (uint4){0u, 0u, 0u, 0u};
    return;
  }
  const float4* p = (const float4*)src + (size_t)j * 2;
  float4 a = p[0], b = p[1];
  u16 t[8] = {f2bf(a.x), f2bf(a.y), f2bf(a.z), f2bf(a.w),
              f2bf(b.x), f2bf(b.y), f2bf(b.z), f2bf(b.w)};
  *(uint4*)(dst + (size_t)j * 8) = *(uint4*)t;
}

// out[r*512+c] = bf16(in[c*512+r]) for two 512x512 weights (z selects)
__global__ __launch_bounds__(256) void k_transpose2(const float* __restrict__ in0, u16* __restrict__ out0,
                                                    const float* __restrict__ in1, u16* __restrict__ out1) {
  __shared__ float t[32][33];
  const float* in = blockIdx.z ? in1 : in0;
  u16* out = blockIdx.z ? out1 : out0;
  int bx = blockIdx.x, by = blockIdx.y;
  int tx = threadIdx.x & 31, ty = threadIdx.x >> 5;
  for (int i = ty; i < 32; i += 8) t[i][tx] = in[(size_t)(by * 32 + i) * 512 + bx * 32 + tx];
  __syncthreads();
  for (int i = ty; i < 32; i += 8) out[(size_t)(bx * 32 + i) * 512 + by * 32 + tx] = f2bf(t[tx][i]);
}

// ---------------- sentbias (blocks 0..31) + biasq (block 32) ----------------
__global__ __launch_bounds__(256) void k_sentbias2(const float* __restrict__ sent, const float* __restrict__ masks,
                                                   const float* __restrict__ conv1_w, const float* __restrict__ conv1_b,
                                                   const float* __restrict__ q_w, const float* __restrict__ conv2_b,
                                                   const float* __restrict__ q_b,
                                                   float* __restrict__ biasb, float* __restrict__ biasq) {
  int b = blockIdx.x, tid = threadIdx.x;
  if (b == 32) {
    for (int j = tid; j < 512; j += 256) {
      const float* wr = q_w + (size_t)j * 512;
      float acc = q_b[j];
#pragma unroll 8
      for (int d = 0; d < 512; ++d) acc += wr[d] * conv2_b[d];
      biasq[j] = acc;
    }
    return;
  }
  __shared__ float sm[512];
  for (int d = tid; d < 512; d += 256) {
    float s = 0.f;
#pragma unroll 8
    for (int t = 0; t < 40; ++t) s += sent[(size_t)b * 40 * 512 + (size_t)t * 512 + d] * masks[b * 40 + t];
    sm[d] = s * (1.0f / 40.0f);
  }
  __syncthreads();
  for (int o = tid; o < 512; o += 256) {
    const float* wr = conv1_w + (size_t)o * 1024 + 512;
    float acc = conv1_b[o];
#pragma unroll 8
    for (int c = 0; c < 512; ++c) acc += sm[c] * wr[c];
    biasb[b * 512 + o] = acc;
  }
}

// ---------------- m97-style GEMM: C = X(Mx512) @ W(Nx512)^T ----------------
// 128x128 tile, 4 waves (2x2), each 64x64. global_load_lds staging, XOR-swizzled
// LDS (unpadded 128B rows): element (r, cg) at LDS r*64 + (cg^(r&7))*8 (u16).
// biasMode: 0 none, 1 per-col bias[col], 2 per-batch-row bias[(row/196)*512+col]
__global__ __launch_bounds__(256) void k_gemm128(const u16* __restrict__ X, const u16* __restrict__ W,
                                                 u16* __restrict__ out, const float* __restrict__ bias,
                                                 int N, int biasMode) {
  __shared__ u16 As[128 * 64];
  __shared__ u16 Bs[128 * 64];
  const int tid = threadIdx.x;
  const int wave = tid >> 6, lane = tid & 63, quad = lane >> 4, l15 = lane & 15;
  const int wr = wave & 1, wc = wave >> 1;
  const int tileM = blockIdx.x * 128, tileN = blockIdx.y * 128;
  const int r8 = lane >> 3;              // row within 8-row group
  const int scg = (lane & 7) ^ r8;       // swizzled source 16B-chunk
  const f32x4 z = {0.f, 0.f, 0.f, 0.f};
  f32x4 acc[4][4];
#pragma unroll
  for (int s = 0; s < 4; ++s)
#pragma unroll
    for (int t = 0; t < 4; ++t) acc[s][t] = z;
  const u16* xb = X + (size_t)tileM * 512;
  const u16* wb = W + (size_t)tileN * 512;
  for (int kc = 0; kc < 512; kc += 64) {
#pragma unroll
    for (int i = wave; i < 32; i += 4) {
      if (i < 16) {
        int rb = i * 8;
        gll16(xb + (size_t)(rb + r8) * 512 + kc + scg * 8, &As[rb * 64]);
      } else {
        int rb = (i - 16) * 8;
        gll16(wb + (size_t)(rb + r8) * 512 + kc + scg * 8, &Bs[rb * 64]);
      }
    }
    __syncthreads();
#pragma unroll
    for (int kk = 0; kk < 64; kk += 32) {
      const int swz = ((((kk >> 3) + quad) ^ (l15 & 7)) * 8);
      bf16x8 af[4], bf[4];
#pragma unroll
      for (int s = 0; s < 4; ++s) af[s] = *(const bf16x8*)&As[(wr * 64 + s * 16 + l15) * 64 + swz];
#pragma unroll
      for (int t = 0; t < 4; ++t) bf[t] = *(const bf16x8*)&Bs[(wc * 64 + t * 16 + l15) * 64 + swz];
#pragma unroll
      for (int s = 0; s < 4; ++s)
#pragma unroll
        for (int t = 0; t < 4; ++t)
          acc[s][t] = __builtin_amdgcn_mfma_f32_16x16x32_bf16(af[s], bf[t], acc[s][t], 0, 0, 0);
    }
    __syncthreads();
  }
#pragma unroll
  for (int s = 0; s < 4; ++s) {
    int row0 = tileM + wr * 64 + s * 16 + quad * 4;
#pragma unroll
    for (int t = 0; t < 4; ++t) {
      int col = tileN + wc * 64 + t * 16 + l15;
      float bv = (biasMode == 1) ? bias[col] : 0.0f;
#pragma unroll
      for (int r = 0; r < 4; ++r) {
        int row = row0 + r;
        float v = acc[s][t][r] + bv;
        if (biasMode == 2) v += bias[(row / 196) * 512 + col];
        out[(size_t)row * N + col] = f2bf(v);
      }
    }
  }
}

// ---------------- MFMA attention: one block (4 waves) per (b,h) ----------------
__global__ __launch_bounds__(256, 1) void k_attn2(const u16* __restrict__ qkv, u16* __restrict__ o_out) {
  const int b = blockIdx.x >> 3, h = blockIdx.x & 7;
  __shared__ u16 Ks[208 * 72];
  __shared__ u16 Vt[64 * 232];
  __shared__ u16 Ps[4][16 * 232];
  const int tid = threadIdx.x;
  const int wave = tid >> 6, lane = tid & 63, quad = lane >> 4, l15 = lane & 15;
  const size_t base = (size_t)b * 196 * 1536 + (size_t)h * 64;

  for (int i = tid; i < 64 * 232 / 4; i += 256) ((unsigned long long*)Vt)[i] = 0ULL;
  for (int i = tid; i < 4 * 16 * 24; i += 256) {
    int w = i / 384, rem = i - w * 384;
    int r = rem / 24, c = rem - r * 24;
    Ps[w][r * 232 + 208 + c] = 0;
  }
  __syncthreads();

  for (int idx = tid; idx < 208 * 8; idx += 256) {
    int r = idx >> 3, c = (idx & 7) * 8;
    uint4 v = {0, 0, 0, 0};
    if (r < 196) v = *(const uint4*)&qkv[base + 512 + (size_t)r * 1536 + c];
    *(uint4*)&Ks[r * 72 + c] = v;
  }
  for (int idx = tid; idx < 196 * 8; idx += 256) {
    int p = idx >> 3, f0 = (idx & 7) * 8;
    uint4 v = *(const uint4*)&qkv[base + 1024 + (size_t)p * 1536 + f0];
    u16 t[8]; *(uint4*)t = v;
#pragma unroll
    for (int j = 0; j < 8; ++j) Vt[(f0 + j) * 232 + p] = t[j];
  }
  bf16x8 qz = {0, 0, 0, 0, 0, 0, 0, 0};
  bf16x8 qf[4][2];
#pragma unroll
  for (int i = 0; i < 4; ++i) {
    int s = wave + i * 4;
    int row = s * 16 + l15;
#pragma unroll
    for (int c = 0; c < 2; ++c) {
      bf16x8 v = qz;
      if (s < 13 && row < 196)
        v = *(const bf16x8*)&qkv[base + (size_t)row * 1536 + c * 32 + quad * 8];
      qf[i][c] = v;
    }
  }
  __syncthreads();

  const f32x4 z = {0.f, 0.f, 0.f, 0.f};
  for (int i = 0; i < 4; ++i) {
    int s = wave + i * 4;
    if (s >= 13) break;
    f32x4 acc[13];
#pragma unroll
    for (int nt = 0; nt < 13; ++nt) acc[nt] = z;
#pragma unroll
    for (int c = 0; c < 2; ++c) {
      bf16x8 a = qf[i][c];
#pragma unroll
      for (int nt = 0; nt < 13; ++nt) {
        bf16x8 bfr = *(const bf16x8*)&Ks[(nt * 16 + l15) * 72 + c * 32 + quad * 8];
        acc[nt] = __builtin_amdgcn_mfma_f32_16x16x32_bf16(a, bfr, acc[nt], 0, 0, 0);
      }
    }
#pragma unroll
    for (int r = 0; r < 4; ++r) {
      float m = -3e38f;
#pragma unroll
      for (int nt = 0; nt < 13; ++nt) {
        float sv = acc[nt][r] * 0.125f;
        acc[nt][r] = sv;
        if (nt < 12 || l15 < 4) m = fmaxf(m, sv);
      }
#pragma unroll
      for (int off = 1; off < 16; off <<= 1) m = fmaxf(m, __shfl_xor(m, off));
      float ssum = 0.f;
#pragma unroll
      for (int nt = 0; nt < 13; ++nt) {
        float p = (nt < 12 || l15 < 4) ? __expf(acc[nt][r] - m) : 0.f;
        acc[nt][r] = p;
        ssum += p;
      }
#pragma unroll
      for (int off = 1; off < 16; off <<= 1) ssum += __shfl_xor(ssum, off);
      float is = 1.0f / ssum;
      int row = quad * 4 + r;
#pragma unroll
      for (int nt = 0; nt < 13; ++nt) {
        float v = acc[nt][r] * is;
        float vx = __shfl_xor(v, 1);
        if ((l15 & 1) == 0) {
          u32 pk = (u32)f2bf(v) | ((u32)f2bf(vx) << 16);
          *(u32*)&Ps[wave][row * 232 + nt * 16 + l15] = pk;
        }
      }
    }
    f32x4 oacc[4] = {z, z, z, z};
#pragma unroll
    for (int kc = 0; kc < 7; ++kc) {
      bf16x8 a = *(const bf16x8*)&Ps[wave][l15 * 232 + kc * 32 + quad * 8];
#pragma unroll
      for (int nt = 0; nt < 4; ++nt) {
        bf16x8 bfr = *(const bf16x8*)&Vt[(nt * 16 + l15) * 232 + kc * 32 + quad * 8];
        oacc[nt] = __builtin_amdgcn_mfma_f32_16x16x32_bf16(a, bfr, oacc[nt], 0, 0, 0);
      }
    }
#pragma unroll
    for (int nt = 0; nt < 4; ++nt) {
#pragma unroll
      for (int r = 0; r < 4; ++r) {
        int row = s * 16 + quad * 4 + r;
        if (row < 196)
          o_out[((size_t)b * 196 + row) * 512 + h * 64 + nt * 16 + l15] = f2bf(oacc[nt][r]);
      }
    }
  }
}

// ---------------- logits: QL(6272x512) @ KL_b(196x512)^T with fused row/col max ----------------
// grid (49,32): 128 rows x 208 cols. async swizzled staging; waves own strips {w, w+4}.
__global__ __launch_bounds__(256) void k_logits3(const u16* __restrict__ QL, const u16* __restrict__ KL,
                                                 u32* __restrict__ rowmax, u32* __restrict__ colmax) {
  const int row0 = blockIdx.x * 128;
  const int b = blockIdx.y;
  __shared__ u16 As[128 * 64];        // 16 KB
  __shared__ u16 Bs[208 * 64];        // 26 KB
  __shared__ float colred[2][4 * 208];// 6.5 KB
  const int tid = threadIdx.x;
  const int wave = tid >> 6, lane = tid & 63, quad = lane >> 4, l15 = lane & 15;
  const int a0 = row0 / 196;
  const int lsplit = (a0 + 1) * 196 - row0;
  const int r8 = lane >> 3, scg = (lane & 7) ^ r8;
  const f32x4 z = {0.f, 0.f, 0.f, 0.f};
  f32x4 acc[2][13];
#pragma unroll
  for (int s = 0; s < 2; ++s)
#pragma unroll
    for (int nt = 0; nt < 13; ++nt) acc[s][nt] = z;
  const u16* qbase = QL + (size_t)row0 * 512;
  const u16* kbase = KL + (size_t)b * 196 * 512;

  for (int kc = 0; kc < 512; kc += 64) {
    for (int i = wave; i < 42; i += 4) {
      if (i < 16) {
        int rb = i * 8;
        gll16(qbase + (size_t)(rb + r8) * 512 + kc + scg * 8, &As[rb * 64]);
      } else {
        int rb = (i - 16) * 8;
        int rr = rb + r8; if (rr > 195) rr = 195; // pad rows dup row195; masked in epilogue
        gll16(kbase + (size_t)rr * 512 + kc + scg * 8, &Bs[rb * 64]);
      }
    }
    __syncthreads();
#pragma unroll
    for (int kk = 0; kk < 64; kk += 32) {
      const int swz = ((((kk >> 3) + quad) ^ (l15 & 7)) * 8);
      bf16x8 af0 = *(const bf16x8*)&As[(wave * 16 + l15) * 64 + swz];
      bf16x8 af1 = *(const bf16x8*)&As[((wave + 4) * 16 + l15) * 64 + swz];
#pragma unroll
      for (int nt = 0; nt < 13; ++nt) {
        bf16x8 bfr = *(const bf16x8*)&Bs[(nt * 16 + l15) * 64 + swz];
        acc[0][nt] = __builtin_amdgcn_mfma_f32_16x16x32_bf16(af0, bfr, acc[0][nt], 0, 0, 0);
        acc[1][nt] = __builtin_amdgcn_mfma_f32_16x16x32_bf16(af1, bfr, acc[1][nt], 0, 0, 0);
      }
    }
    __syncthreads();
  }
  // ---- rowmax (masked cols >=196; keyed atomic per row) ----
#pragma unroll
  for (int s = 0; s < 2; ++s) {
#pragma unroll
    for (int r = 0; r < 4; ++r) {
      float m = -3e38f;
#pragma unroll
      for (int nt = 0; nt < 13; ++nt)
        if (nt < 12 || l15 < 4) m = fmaxf(m, acc[s][nt][r]);
#pragma unroll
      for (int off = 8; off > 0; off >>= 1) m = fmaxf(m, __shfl_xor(m, off, 16));
      if (l15 == 0) {
        int lr = (wave + s * 4) * 16 + quad * 4 + r;
        int aa = a0, ll = row0 - a0 * 196 + lr;
        if (ll >= 196) { aa += 1; ll -= 196; }
        atomicMax(&rowmax[((size_t)aa * 32 + b) * 196 + ll], encf(m));
      }
    }
  }
  // ---- colmax: segment rows by a before cross-quad shuffles ----
#pragma unroll
  for (int nt = 0; nt < 13; ++nt) {
    float cm0 = -3e38f, cm1 = -3e38f;
#pragma unroll
    for (int s = 0; s < 2; ++s)
#pragma unroll
      for (int r = 0; r < 4; ++r) {
        int lr = (wave + s * 4) * 16 + quad * 4 + r;
        float v = acc[s][nt][r];
        if (lr < lsplit) cm0 = fmaxf(cm0, v); else cm1 = fmaxf(cm1, v);
      }
    cm0 = fmaxf(cm0, __shfl_xor(cm0, 16)); cm0 = fmaxf(cm0, __shfl_xor(cm0, 32));
    cm1 = fmaxf(cm1, __shfl_xor(cm1, 16)); cm1 = fmaxf(cm1, __shfl_xor(cm1, 32));
    if (quad == 0) {
      colred[0][wave * 208 + nt * 16 + l15] = cm0;
      colred[1][wave * 208 + nt * 16 + l15] = cm1;
    }
  }
  __syncthreads();
  for (int c = tid; c < 196; c += 256) {
    float m0 = fmaxf(fmaxf(colred[0][c], colred[0][208 + c]), fmaxf(colred[0][416 + c], colred[0][624 + c]));
    atomicMax(&colmax[((size_t)a0 * 32 + b) * 196 + c], encf(m0));
    if (lsplit < 128) {
      float m1 = fmaxf(fmaxf(colred[1][c], colred[1][208 + c]), fmaxf(colred[1][416 + c], colred[1][624 + c]));
      atomicMax(&colmax[((size_t)(a0 + 1) * 32 + b) * 196 + c], encf(m1));
    }
  }
}

// ---------------- final: S matrix + symmetric cross-entropy ----------------
__global__ __launch_bounds__(1024) void k_final(const u32* __restrict__ maxbuf,
                                                const float* __restrict__ logit_scale, float* __restrict__ out) {
  __shared__ float S[1024];
  __shared__ float terms[64];
  int tid = threadIdx.x;
  float sc = 0.5f * __expf(logit_scale[0]);
  const uint4* rp = (const uint4*)(maxbuf + (size_t)tid * 196);
  const uint4* cp = (const uint4*)(maxbuf + 200704 + (size_t)tid * 196);
  float s = 0.f;
#pragma unroll 7
  for (int i = 0; i < 49; ++i) {
    uint4 v = rp[i]; s += decf2(v.x) + decf2(v.y) + decf2(v.z) + decf2(v.w);
    uint4 w = cp[i]; s += decf2(w.x) + decf2(w.y) + decf2(w.z) + decf2(w.w);
  }
  S[tid] = sc * s * (1.0f / 196.0f);
  __syncthreads();
  if (tid < 64) {
    int aa = tid & 31;
    bool rowMode = tid < 32;
    float mx = -3e38f;
    for (int j = 0; j < 32; ++j) {
      float v = rowMode ? S[aa * 32 + j] : S[j * 32 + aa];
      mx = fmaxf(mx, v);
    }
    float se = 0.f;
    for (int j = 0; j < 32; ++j) {
      float v = rowMode ? S[aa * 32 + j] : S[j * 32 + aa];
      se += __expf(v - mx);
    }
    terms[tid] = S[aa * 33] - (mx + logf(se));
  }
  __syncthreads();
  if (tid == 0) {
    float s2 = 0.f;
    for (int i = 0; i < 64; ++i) s2 += terms[i];
    out[0] = -s2 * (1.0f / 64.0f);
  }
}

// ---------------- host ----------------
extern "C" void kernel_launch(void* const* d_in, const int* in_sizes, int n_in,
                              void* d_out, int out_size, void* d_ws, size_t ws_size,
                              hipStream_t stream) {
  const float* bef       = (const float*)d_in[0];
  const float* sent      = (const float*)d_in[1];
  const float* aft       = (const float*)d_in[2];
  const float* masks     = (const float*)d_in[3];
  const float* conv1_w   = (const float*)d_in[4];
  const float* conv1_b   = (const float*)d_in[5];
  const float* in_proj_w = (const float*)d_in[6];
  const float* out_proj_w= (const float*)d_in[7];
  const float* conv2_w   = (const float*)d_in[8];
  const float* conv2_b   = (const float*)d_in[9];
  const float* q_w       = (const float*)d_in[10];
  const float* q_b       = (const float*)d_in[11];
  const float* k_w       = (const float*)d_in[12];
  const float* k_b       = (const float*)d_in[13];
  const float* logit_scale = (const float*)d_in[14];
  float* out = (float*)d_out;

  char* ws = (char*)d_ws;
  size_t off = 0;
  auto alloc = [&](size_t bytes) -> char* {
    char* p = ws + off;
    off += (bytes + 255) & ~(size_t)255;
    return p;
  };
  const size_t MROWS = 32 * 196; // 6272
  u16* bef16    = (u16*)alloc(MROWS * 512 * 2);
  u16* aft16    = (u16*)alloc(MROWS * 512 * 2);
  u16* w1a16    = (u16*)alloc(512 * 512 * 2);
  u16* inproj16 = (u16*)alloc(1536 * 512 * 2);
  u16* kw16     = (u16*)alloc(512 * 512 * 2);
  u16* qw16     = (u16*)alloc(512 * 512 * 2);
  u16* wcT16    = (u16*)alloc(512 * 512 * 2);
  u16* woT16    = (u16*)alloc(512 * 512 * 2);
  u16* wt16     = (u16*)alloc(512 * 512 * 2);
  u16* wcomb16  = (u16*)alloc(512 * 512 * 2);
  float* biasb  = (float*)alloc(32 * 512 * 4);
  float* biasq  = (float*)alloc(512 * 4);
  u16* v116     = (u16*)alloc(MROWS * 512 * 2);
  u16* qkv16    = (u16*)alloc(MROWS * 1536 * 2);
  u16* oattn16  = (u16*)alloc(MROWS * 512 * 2);
  u16* QL16     = (u16*)alloc(MROWS * 512 * 2);
  u16* KL16     = (u16*)alloc(MROWS * 512 * 2);
  u32* maxbuf   = (u32*)alloc(2 * 32 * 32 * 196 * 4); // rowmax | colmax
  u32* rowmax   = maxbuf;
  u32* colmax   = maxbuf + 32 * 32 * 196;

  // fused casts + maxbuf zero (1,099,776 items)
  k_prep<<<4296, 256, 0, stream>>>(bef, aft, in_proj_w, k_w, q_w, conv1_w,
                                   bef16, aft16, inproj16, kw16, qw16, w1a16, (uint4*)maxbuf);
  k_transpose2<<<dim3(16, 16, 2), 256, 0, stream>>>(conv2_w, wcT16, out_proj_w, woT16);
  k_sentbias2<<<33, 256, 0, stream>>>(sent, masks, conv1_w, conv1_b, q_w, conv2_b, q_b, biasb, biasq);
  // weight composition: Wcomb = Wq @ Wc @ Wo
  k_gemm128<<<dim3(4, 4), 256, 0, stream>>>(qw16, wcT16, wt16, nullptr, 512, 0);
  k_gemm128<<<dim3(4, 4), 256, 0, stream>>>(wt16, woT16, wcomb16, nullptr, 512, 0);
  // v1 = bef @ W1a^T + biasb[b]
  k_gemm128<<<dim3(49, 4), 256, 0, stream>>>(bef16, w1a16, v116, biasb, 512, 2);
  // qkv = v1 @ in_proj^T
  k_gemm128<<<dim3(49, 12), 256, 0, stream>>>(v116, inproj16, qkv16, nullptr, 1536, 0);
  // attention (MFMA)
  k_attn2<<<256, 256, 0, stream>>>(qkv16, oattn16);
  // QL = o_attn @ Wcomb^T + biasq ;  KL = aft @ k_w^T + k_b
  k_gemm128<<<dim3(49, 4), 256, 0, stream>>>(oattn16, wcomb16, QL16, biasq, 512, 1);
  k_gemm128<<<dim3(49, 4), 256, 0, stream>>>(aft16, kw16, KL16, k_b, 512, 1);
  // logits reductions
  k_logits3<<<dim3(49, 32), 256, 0, stream>>>(QL16, KL16, rowmax, colmax);
  // final loss
  k_final<<<1, 1024, 0, stream>>>(maxbuf, logit_scale, out);
}